// Round 10
// baseline (129.800 us; speedup 1.0000x reference)
//
#include <hip/hip_runtime.h>
#include <hip/hip_bf16.h>

#define Bb 8
#define Nn 8192
#define Ss 4
#define Dd 256
#define MTOT (Bb*Nn)   // 65536

typedef unsigned short u16;
typedef unsigned int u32;
typedef short short8 __attribute__((ext_vector_type(8)));
typedef unsigned short u16x4 __attribute__((ext_vector_type(4)));
typedef unsigned int u32x4 __attribute__((ext_vector_type(4)));
typedef float f32x4 __attribute__((ext_vector_type(4)));

static __device__ __forceinline__ float bf2f(u16 v) {
  union { unsigned int u; float f; } x; x.u = ((unsigned int)v) << 16; return x.f;
}
static __device__ __forceinline__ u16 f2bf(float f) {
  union { float f; unsigned int u; } x; x.f = f;
  unsigned int u = x.u;
  return (u16)((u + 0x7fffu + ((u >> 16) & 1u)) >> 16);  // RNE
}
// hardware packed f32->bf16 (RNE), lo=a, hi=b
static __device__ __forceinline__ u32 cvtpk(float a, float b) {
  u32 r;
  asm("v_cvt_pk_bf16_f32 %0, %1, %2" : "=v"(r) : "v"(a), "v"(b));
  return r;
}

// tanh-form GELU as a sigmoid: gelu(x) = x * sigmoid(1.5957691*(x + 0.044715 x^3))
static __device__ __forceinline__ float gelu_fast(float x) {
  float x2 = x * x;
  float z = x * (-2.3021277f - 0.10294456f * x2);
  float e = __builtin_amdgcn_exp2f(z);
  return x * __builtin_amdgcn_rcpf(1.0f + e);
}

// ---------------------------------------------------------------------------
// prep (weights only): W1 -> W1t bf16 (transposed); W2 -> W2t bf16.
// ---------------------------------------------------------------------------
__global__ __launch_bounds__(256) void prep_w(
    const float* __restrict__ W1, const float* __restrict__ W2,
    u16* __restrict__ W1t, u16* __restrict__ W2t)
{
  int bid = blockIdx.x, t = threadIdx.x;
  if (bid < 768) {
    int j = bid * 256 + t;             // j = n*256 + k
    int n = j >> 8, k = j & 255;
    int tb = n >> 8, d = n & 255;
    W1t[j] = f2bf(W1[(size_t)(tb * 256 + k) * 256 + d]);
  } else {
    int j = (bid - 768) * 256 + t;
    int n = j >> 8, k = j & 255;
    W2t[j] = f2bf(W2[(size_t)k * 256 + n]);
  }
}

// ---------------------------------------------------------------------------
// 128x128-tile bf16 MFMA GEMM, K=256, BK=64, 4 waves (2x2).
// 1D grid, n-inner, XCD-chunk swizzle; T2 LDS swizzle.
// MODE 0: A reg-staged from f32 with HW v_cvt_pk_bf16_f32 (fuses the old
//         x->bf16 prep pass), swizzled ds_write; out bf16.
// MODE 1: A bf16 via global_load_lds (source pre-swizzle); out f32 + bias.
// B always bf16 via global_load_lds with source pre-swizzle.
// ---------------------------------------------------------------------------
template<int MODE, int NBLK>
__global__ __launch_bounds__(256) void gemm128(
    const float* __restrict__ Af32, const u16* __restrict__ Abf,
    const u16* __restrict__ Btg,
    void* __restrict__ Outv, const float* __restrict__ bias, int ldOut)
{
  __shared__ u16 As[128 * 64];
  __shared__ u16 Bs[128 * 64];
  const int t = threadIdx.x;
  const int w = t >> 6, lane = t & 63;
  const int wm = (w >> 1) * 64, wn = (w & 1) * 64;
  const int lr = lane & 15;
  const int lk = (lane >> 4) * 8;

  const int cpx = gridDim.x >> 3;
  const int bid = blockIdx.x;
  const int swz = (bid & 7) * cpx + (bid >> 3);
  const int n0 = (swz % NBLK) * 128;
  const size_t m0 = (size_t)(swz / NBLK) * 128;

  f32x4 acc[4][4];
#pragma unroll
  for (int m = 0; m < 4; ++m)
#pragma unroll
    for (int n = 0; n < 4; ++n)
      acc[m][n] = (f32x4){0.f, 0.f, 0.f, 0.f};

  for (int kt = 0; kt < 4; ++kt) {
    // B tile: async glds, source column-chunk pre-swizzled
#pragma unroll
    for (int pass = 0; pass < 4; ++pass) {
      int c = pass * 256 + t;
      int row = c >> 3, cc = c & 7;
      int scc = cc ^ (row & 7);
      const u16* gb = Btg + (size_t)(n0 + row) * 256 + kt * 64 + scc * 8;
      u16* lb = Bs + pass * 2048 + (t & 192) * 8;
      __builtin_amdgcn_global_load_lds(
          (const __attribute__((address_space(1))) void*)gb,
          (__attribute__((address_space(3))) void*)lb, 16, 0, 0);
    }
    if (MODE == 0) {
      // A tile: reg-stage f32 -> HW cvt_pk -> swizzled ds_write_b128.
      // LDS image identical to the glds-source-pre-swizzle one.
#pragma unroll
      for (int half = 0; half < 2; ++half) {
        int c = half * 256 + t;           // 512 chunks of 16 cols
        int row = c >> 2, seg = c & 3;
        const float* gx = Af32 + (m0 + row) * 256 + kt * 64 + seg * 16;
        f32x4 v0 = *(const f32x4*)(gx + 0);
        f32x4 v1 = *(const f32x4*)(gx + 4);
        f32x4 v2 = *(const f32x4*)(gx + 8);
        f32x4 v3 = *(const f32x4*)(gx + 12);
        u32x4 p0, p1;
        p0[0] = cvtpk(v0[0], v0[1]); p0[1] = cvtpk(v0[2], v0[3]);
        p0[2] = cvtpk(v1[0], v1[1]); p0[3] = cvtpk(v1[2], v1[3]);
        p1[0] = cvtpk(v2[0], v2[1]); p1[1] = cvtpk(v2[2], v2[3]);
        p1[2] = cvtpk(v3[0], v3[1]); p1[3] = cvtpk(v3[2], v3[3]);
        int bidx = row * 64 + seg * 16;
        int sw = (row & 7) << 3;
        *(u32x4*)&As[(bidx + 0) ^ sw] = p0;
        *(u32x4*)&As[(bidx + 8) ^ sw] = p1;
      }
    } else {
#pragma unroll
      for (int pass = 0; pass < 4; ++pass) {
        int c = pass * 256 + t;
        int row = c >> 3, cc = c & 7;
        int scc = cc ^ (row & 7);
        const u16* ga = Abf + (m0 + row) * 256 + kt * 64 + scc * 8;
        u16* la = As + pass * 2048 + (t & 192) * 8;
        __builtin_amdgcn_global_load_lds(
            (const __attribute__((address_space(1))) void*)ga,
            (__attribute__((address_space(3))) void*)la, 16, 0, 0);
      }
    }
    __syncthreads();
#pragma unroll
    for (int kk = 0; kk < 2; ++kk) {
      short8 af[4], bfr[4];
#pragma unroll
      for (int m = 0; m < 4; ++m) {
        int rA = wm + m * 16 + lr;
        af[m] = *(const short8*)&As[(rA * 64 + kk * 32 + lk) ^ ((rA & 7) << 3)];
      }
#pragma unroll
      for (int n = 0; n < 4; ++n) {
        int rB = wn + n * 16 + lr;
        bfr[n] = *(const short8*)&Bs[(rB * 64 + kk * 32 + lk) ^ ((rB & 7) << 3)];
      }
#pragma unroll
      for (int m = 0; m < 4; ++m)
#pragma unroll
        for (int n = 0; n < 4; ++n)
          acc[m][n] = __builtin_amdgcn_mfma_f32_16x16x32_bf16(
              af[m], bfr[n], acc[m][n], 0, 0, 0);
    }
    __syncthreads();
  }

#pragma unroll
  for (int m = 0; m < 4; ++m) {
    int rbase = wm + m * 16 + ((lane >> 4) << 2);
#pragma unroll
    for (int n = 0; n < 4; ++n) {
      int col = n0 + wn + n * 16 + (lane & 15);
#pragma unroll
      for (int rr = 0; rr < 4; ++rr) {
        size_t row = m0 + rbase + rr;
        if (MODE == 0) {
          ((u16*)Outv)[row * (size_t)ldOut + col] = f2bf(acc[m][n][rr]);
        } else {
          ((float*)Outv)[row * (size_t)ldOut + col] = acc[m][n][rr] + bias[col];
        }
      }
    }
  }
}

// ---------------------------------------------------------------------------
// gather + fast GELU + mean over S.  One wave per output row.
// Indices in SGPRs, all 8 gathers in flight; chunked XCD swizzle.
// (R9 form — measured at the gather's mixed VALU/memory operating point.)
// ---------------------------------------------------------------------------
__global__ __launch_bounds__(256) void gather_gelu_mean(
    const u16* __restrict__ ABC, const int* __restrict__ ji,
    const int* __restrict__ ki, const float* __restrict__ b1,
    u16* __restrict__ Hm)
{
  int t = threadIdx.x, w = t >> 6, lane = t & 63;
  const int cpx = gridDim.x >> 3;
  const int bid = blockIdx.x;
  const int swz = (bid & 7) * cpx + (bid >> 3);
  size_t r = (size_t)swz * 4 + w;
  int base = ((int)(r >> 13)) << 13;   // batch row offset
  int d0 = lane * 4;

  u16x4 av = *(const u16x4*)(ABC + r * 768 + d0);
  f32x4 bias = *(const f32x4*)&b1[d0];

  const int* jr = ji + r * 4;
  const int* kr = ki + r * 4;
  int j0 = __builtin_amdgcn_readfirstlane(jr[0]);
  int j1 = __builtin_amdgcn_readfirstlane(jr[1]);
  int j2 = __builtin_amdgcn_readfirstlane(jr[2]);
  int j3 = __builtin_amdgcn_readfirstlane(jr[3]);
  int k0 = __builtin_amdgcn_readfirstlane(kr[0]);
  int k1 = __builtin_amdgcn_readfirstlane(kr[1]);
  int k2 = __builtin_amdgcn_readfirstlane(kr[2]);
  int k3 = __builtin_amdgcn_readfirstlane(kr[3]);

  u16x4 bv0 = *(const u16x4*)(ABC + (size_t)(base + j0) * 768 + 256 + d0);
  u16x4 bv1 = *(const u16x4*)(ABC + (size_t)(base + j1) * 768 + 256 + d0);
  u16x4 bv2 = *(const u16x4*)(ABC + (size_t)(base + j2) * 768 + 256 + d0);
  u16x4 bv3 = *(const u16x4*)(ABC + (size_t)(base + j3) * 768 + 256 + d0);
  u16x4 cv0 = *(const u16x4*)(ABC + (size_t)(base + k0) * 768 + 512 + d0);
  u16x4 cv1 = *(const u16x4*)(ABC + (size_t)(base + k1) * 768 + 512 + d0);
  u16x4 cv2 = *(const u16x4*)(ABC + (size_t)(base + k2) * 768 + 512 + d0);
  u16x4 cv3 = *(const u16x4*)(ABC + (size_t)(base + k3) * 768 + 512 + d0);

  float a0 = bf2f(av[0]) + bias[0];
  float a1 = bf2f(av[1]) + bias[1];
  float a2 = bf2f(av[2]) + bias[2];
  float a3 = bf2f(av[3]) + bias[3];

  float acc0, acc1, acc2, acc3;
  {
    float x0 = a0 + bf2f(bv0[0]) + bf2f(cv0[0]);
    float x1 = a1 + bf2f(bv0[1]) + bf2f(cv0[1]);
    float x2 = a2 + bf2f(bv0[2]) + bf2f(cv0[2]);
    float x3 = a3 + bf2f(bv0[3]) + bf2f(cv0[3]);
    acc0 = gelu_fast(x0); acc1 = gelu_fast(x1);
    acc2 = gelu_fast(x2); acc3 = gelu_fast(x3);
  }
  {
    float x0 = a0 + bf2f(bv1[0]) + bf2f(cv1[0]);
    float x1 = a1 + bf2f(bv1[1]) + bf2f(cv1[1]);
    float x2 = a2 + bf2f(bv1[2]) + bf2f(cv1[2]);
    float x3 = a3 + bf2f(bv1[3]) + bf2f(cv1[3]);
    acc0 += gelu_fast(x0); acc1 += gelu_fast(x1);
    acc2 += gelu_fast(x2); acc3 += gelu_fast(x3);
  }
  {
    float x0 = a0 + bf2f(bv2[0]) + bf2f(cv2[0]);
    float x1 = a1 + bf2f(bv2[1]) + bf2f(cv2[1]);
    float x2 = a2 + bf2f(bv2[2]) + bf2f(cv2[2]);
    float x3 = a3 + bf2f(bv2[3]) + bf2f(cv2[3]);
    acc0 += gelu_fast(x0); acc1 += gelu_fast(x1);
    acc2 += gelu_fast(x2); acc3 += gelu_fast(x3);
  }
  {
    float x0 = a0 + bf2f(bv3[0]) + bf2f(cv3[0]);
    float x1 = a1 + bf2f(bv3[1]) + bf2f(cv3[1]);
    float x2 = a2 + bf2f(bv3[2]) + bf2f(cv3[2]);
    float x3 = a3 + bf2f(bv3[3]) + bf2f(cv3[3]);
    acc0 += gelu_fast(x0); acc1 += gelu_fast(x1);
    acc2 += gelu_fast(x2); acc3 += gelu_fast(x3);
  }

  u16x4 hv;
  hv[0] = f2bf(acc0 * 0.25f);
  hv[1] = f2bf(acc1 * 0.25f);
  hv[2] = f2bf(acc2 * 0.25f);
  hv[3] = f2bf(acc3 * 0.25f);
  *(u16x4*)(Hm + r * 256 + d0) = hv;
}

// ---------------------------------------------------------------------------
extern "C" void kernel_launch(void* const* d_in, const int* in_sizes, int n_in,
                              void* d_out, int out_size, void* d_ws, size_t ws_size,
                              hipStream_t stream) {
  (void)in_sizes; (void)n_in; (void)out_size; (void)ws_size;
  const float* x  = (const float*)d_in[0];
  const int*   ji = (const int*)d_in[1];
  const int*   ki = (const int*)d_in[2];
  const float* W1 = (const float*)d_in[3];
  const float* b1 = (const float*)d_in[4];
  const float* W2 = (const float*)d_in[5];
  const float* b2 = (const float*)d_in[6];
  float* out = (float*)d_out;

  char* ws = (char*)d_ws;
  u16* ABC = (u16*)ws;  ws += (size_t)MTOT * 768 * 2;   // 100.7 MB
  u16* Hm  = (u16*)ws;  ws += (size_t)MTOT * 256 * 2;   // 33.5 MB
  u16* W1t = (u16*)ws;  ws += 768 * 256 * 2;
  u16* W2t = (u16*)ws;  ws += 256 * 256 * 2;

  prep_w<<<1024, 256, 0, stream>>>(W1, W2, W1t, W2t);

  gemm128<0, 6><<<(MTOT / 128) * 6, 256, 0, stream>>>(
      x, nullptr, W1t, (void*)ABC, nullptr, 768);

  gather_gelu_mean<<<MTOT / 4, 256, 0, stream>>>(ABC, ji, ki, b1, Hm);

  gemm128<1, 2><<<(MTOT / 128) * 2, 256, 0, stream>>>(
      nullptr, Hm, W2t, (void*)out, b2, 256);
}

// Round 11
// 127.499 us; speedup vs baseline: 1.0180x; 1.0180x over previous
//
#include <hip/hip_runtime.h>
#include <hip/hip_bf16.h>

#define Bb 8
#define Nn 8192
#define Ss 4
#define Dd 256
#define MTOT (Bb*Nn)   // 65536

typedef unsigned short u16;
typedef unsigned int u32;
typedef short short8 __attribute__((ext_vector_type(8)));
typedef unsigned short u16x4 __attribute__((ext_vector_type(4)));
typedef unsigned int u32x4 __attribute__((ext_vector_type(4)));
typedef float f32x4 __attribute__((ext_vector_type(4)));

static __device__ __forceinline__ float bf2f(u16 v) {
  union { unsigned int u; float f; } x; x.u = ((unsigned int)v) << 16; return x.f;
}
static __device__ __forceinline__ u16 f2bf(float f) {
  union { float f; unsigned int u; } x; x.f = f;
  unsigned int u = x.u;
  return (u16)((u + 0x7fffu + ((u >> 16) & 1u)) >> 16);  // RNE
}
// hardware packed f32->bf16 (RNE): lo=bf16(a), hi=bf16(b)
static __device__ __forceinline__ u32 cvtpk(float a, float b) {
  u32 r;
  asm("v_cvt_pk_bf16_f32 %0, %1, %2" : "=v"(r) : "v"(a), "v"(b));
  return r;
}

// tanh-form GELU as a sigmoid
static __device__ __forceinline__ float gelu_fast(float x) {
  float x2 = x * x;
  float z = x * (-2.3021277f - 0.10294456f * x2);
  float e = __builtin_amdgcn_exp2f(z);
  return x * __builtin_amdgcn_rcpf(1.0f + e);
}

// ---------------------------------------------------------------------------
// prep (weights only): W1 -> W1t bf16 (transposed); W2 -> W2t bf16.
// ---------------------------------------------------------------------------
__global__ __launch_bounds__(256) void prep_w(
    const float* __restrict__ W1, const float* __restrict__ W2,
    u16* __restrict__ W1t, u16* __restrict__ W2t)
{
  int bid = blockIdx.x, t = threadIdx.x;
  if (bid < 768) {
    int j = bid * 256 + t;             // j = n*256 + k
    int n = j >> 8, k = j & 255;
    int tb = n >> 8, d = n & 255;
    W1t[j] = f2bf(W1[(size_t)(tb * 256 + k) * 256 + d]);
  } else {
    int j = (bid - 768) * 256 + t;
    int n = j >> 8, k = j & 255;
    W2t[j] = f2bf(W2[(size_t)k * 256 + n]);
  }
}

// ---------------------------------------------------------------------------
// gemm1 fused with x->bf16: A staged as RAW F32 via async global_load_lds
// (32 KB tile), converted to bf16 in the fragment path with HW cvt_pk.
// All staging async (identical barrier structure to the split gemm) --
// fixes R8/R10's sync-load serialization.
// B: bf16 via glds, source pre-swizzled. 128x128 tile, K=256, BK=64.
// 16B-unit XOR swizzle on both A(f32) and B(bf16).
// ---------------------------------------------------------------------------
__global__ __launch_bounds__(256) void gemm1f(
    const float* __restrict__ Xf, const u16* __restrict__ Btg,
    u16* __restrict__ Out)
{
  __shared__ float Asf[128 * 64];   // 32 KB
  __shared__ u16 Bs[128 * 64];      // 16 KB
  const int t = threadIdx.x;
  const int w = t >> 6, lane = t & 63;
  const int wm = (w >> 1) * 64, wn = (w & 1) * 64;
  const int lr = lane & 15;
  const int lk = (lane >> 4) * 8;

  const int cpx = gridDim.x >> 3;
  const int bid = blockIdx.x;
  const int swz = (bid & 7) * cpx + (bid >> 3);
  const int n0 = (swz % 6) * 128;
  const size_t m0 = (size_t)(swz / 6) * 128;

  f32x4 acc[4][4];
#pragma unroll
  for (int m = 0; m < 4; ++m)
#pragma unroll
    for (int n = 0; n < 4; ++n)
      acc[m][n] = (f32x4){0.f, 0.f, 0.f, 0.f};

  for (int kt = 0; kt < 4; ++kt) {
    // B tile bf16: 4 passes, 16B/lane, source chunk pre-swizzled
#pragma unroll
    for (int pass = 0; pass < 4; ++pass) {
      int c = pass * 256 + t;
      int row = c >> 3, cc = c & 7;
      int scc = cc ^ (row & 7);
      const u16* gb = Btg + (size_t)(n0 + row) * 256 + kt * 64 + scc * 8;
      u16* lb = Bs + pass * 2048 + (t & 192) * 8;
      __builtin_amdgcn_global_load_lds(
          (const __attribute__((address_space(1))) void*)gb,
          (__attribute__((address_space(3))) void*)lb, 16, 0, 0);
    }
    // A tile f32: 8 passes, 16B/lane (4 floats), source 16B-unit pre-swizzle
#pragma unroll
    for (int pass = 0; pass < 8; ++pass) {
      int c = pass * 256 + t;          // 2048 chunks: 16 per row
      int row = c >> 4, sub = c & 15;
      int ssub = sub ^ (row & 7);
      const float* ga = Xf + (m0 + row) * 256 + kt * 64 + ssub * 4;
      float* la = Asf + pass * 1024 + (t & 192) * 4;   // wave-uniform base
      __builtin_amdgcn_global_load_lds(
          (const __attribute__((address_space(1))) void*)ga,
          (__attribute__((address_space(3))) void*)la, 16, 0, 0);
    }
    __syncthreads();
#pragma unroll
    for (int kk = 0; kk < 2; ++kk) {
      short8 af[4], bfr[4];
#pragma unroll
      for (int m = 0; m < 4; ++m) {
        int rA = wm + m * 16 + lr;
        int sb = kk * 8 + ((lane >> 4) << 1);        // 16B-unit index (4 floats)
        f32x4 a0 = *(const f32x4*)&Asf[rA * 64 + ((sb ^ (rA & 7)) << 2)];
        f32x4 a1 = *(const f32x4*)&Asf[rA * 64 + (((sb + 1) ^ (rA & 7)) << 2)];
        union { u32x4 u; short8 s; } pk;
        pk.u[0] = cvtpk(a0[0], a0[1]);
        pk.u[1] = cvtpk(a0[2], a0[3]);
        pk.u[2] = cvtpk(a1[0], a1[1]);
        pk.u[3] = cvtpk(a1[2], a1[3]);
        af[m] = pk.s;
      }
#pragma unroll
      for (int n = 0; n < 4; ++n) {
        int rB = wn + n * 16 + lr;
        bfr[n] = *(const short8*)&Bs[(rB * 64 + kk * 32 + lk) ^ ((rB & 7) << 3)];
      }
#pragma unroll
      for (int m = 0; m < 4; ++m)
#pragma unroll
        for (int n = 0; n < 4; ++n)
          acc[m][n] = __builtin_amdgcn_mfma_f32_16x16x32_bf16(
              af[m], bfr[n], acc[m][n], 0, 0, 0);
    }
    __syncthreads();
  }

  // epilogue: col = lane&15, row = (lane>>4)*4 + rr; packed cvt
#pragma unroll
  for (int m = 0; m < 4; ++m) {
    int rbase = wm + m * 16 + ((lane >> 4) << 2);
#pragma unroll
    for (int n = 0; n < 4; ++n) {
      int col = n0 + wn + n * 16 + (lane & 15);
      u32 w01 = cvtpk(acc[m][n][0], acc[m][n][1]);
      u32 w23 = cvtpk(acc[m][n][2], acc[m][n][3]);
      size_t rowb = m0 + rbase;
      Out[(rowb + 0) * 768 + col] = (u16)w01;
      Out[(rowb + 1) * 768 + col] = (u16)(w01 >> 16);
      Out[(rowb + 2) * 768 + col] = (u16)w23;
      Out[(rowb + 3) * 768 + col] = (u16)(w23 >> 16);
    }
  }
}

// ---------------------------------------------------------------------------
// gemm2: Hm(bf16) @ W2t + b2 -> f32.  128x128 tile, glds both operands,
// T2 swizzle, n-inner XCD swizzle (NBLK=2).
// ---------------------------------------------------------------------------
__global__ __launch_bounds__(256) void gemm2k(
    const u16* __restrict__ Ag, const u16* __restrict__ Btg,
    float* __restrict__ Outf, const float* __restrict__ bias)
{
  __shared__ u16 As[128 * 64];
  __shared__ u16 Bs[128 * 64];
  const int t = threadIdx.x;
  const int w = t >> 6, lane = t & 63;
  const int wm = (w >> 1) * 64, wn = (w & 1) * 64;
  const int lr = lane & 15;
  const int lk = (lane >> 4) * 8;

  const int cpx = gridDim.x >> 3;
  const int bid = blockIdx.x;
  const int swz = (bid & 7) * cpx + (bid >> 3);
  const int n0 = (swz % 2) * 128;
  const size_t m0 = (size_t)(swz / 2) * 128;

  f32x4 acc[4][4];
#pragma unroll
  for (int m = 0; m < 4; ++m)
#pragma unroll
    for (int n = 0; n < 4; ++n)
      acc[m][n] = (f32x4){0.f, 0.f, 0.f, 0.f};

  for (int kt = 0; kt < 4; ++kt) {
#pragma unroll
    for (int pass = 0; pass < 4; ++pass) {
      int c = pass * 256 + t;
      int row = c >> 3, cc = c & 7;
      int scc = cc ^ (row & 7);
      const u16* ga = Ag + (m0 + row) * 256 + kt * 64 + scc * 8;
      u16* la = As + pass * 2048 + (t & 192) * 8;
      __builtin_amdgcn_global_load_lds(
          (const __attribute__((address_space(1))) void*)ga,
          (__attribute__((address_space(3))) void*)la, 16, 0, 0);
      const u16* gb = Btg + (size_t)(n0 + row) * 256 + kt * 64 + scc * 8;
      u16* lb = Bs + pass * 2048 + (t & 192) * 8;
      __builtin_amdgcn_global_load_lds(
          (const __attribute__((address_space(1))) void*)gb,
          (__attribute__((address_space(3))) void*)lb, 16, 0, 0);
    }
    __syncthreads();
#pragma unroll
    for (int kk = 0; kk < 2; ++kk) {
      short8 af[4], bfr[4];
#pragma unroll
      for (int m = 0; m < 4; ++m) {
        int rA = wm + m * 16 + lr;
        af[m] = *(const short8*)&As[(rA * 64 + kk * 32 + lk) ^ ((rA & 7) << 3)];
      }
#pragma unroll
      for (int n = 0; n < 4; ++n) {
        int rB = wn + n * 16 + lr;
        bfr[n] = *(const short8*)&Bs[(rB * 64 + kk * 32 + lk) ^ ((rB & 7) << 3)];
      }
#pragma unroll
      for (int m = 0; m < 4; ++m)
#pragma unroll
        for (int n = 0; n < 4; ++n)
          acc[m][n] = __builtin_amdgcn_mfma_f32_16x16x32_bf16(
              af[m], bfr[n], acc[m][n], 0, 0, 0);
    }
    __syncthreads();
  }

#pragma unroll
  for (int m = 0; m < 4; ++m) {
    int rbase = wm + m * 16 + ((lane >> 4) << 2);
#pragma unroll
    for (int n = 0; n < 4; ++n) {
      int col = n0 + wn + n * 16 + (lane & 15);
      float bb = bias[col];
#pragma unroll
      for (int rr = 0; rr < 4; ++rr) {
        size_t row = m0 + rbase + rr;
        Outf[row * 256 + col] = acc[m][n][rr] + bb;
      }
    }
  }
}

// ---------------------------------------------------------------------------
// gather + fast GELU + mean over S (R9 form: SGPR indices, 8 gathers in
// flight, chunked XCD swizzle).
// ---------------------------------------------------------------------------
__global__ __launch_bounds__(256) void gather_gelu_mean(
    const u16* __restrict__ ABC, const int* __restrict__ ji,
    const int* __restrict__ ki, const float* __restrict__ b1,
    u16* __restrict__ Hm)
{
  int t = threadIdx.x, w = t >> 6, lane = t & 63;
  const int cpx = gridDim.x >> 3;
  const int bid = blockIdx.x;
  const int swz = (bid & 7) * cpx + (bid >> 3);
  size_t r = (size_t)swz * 4 + w;
  int base = ((int)(r >> 13)) << 13;   // batch row offset
  int d0 = lane * 4;

  u16x4 av = *(const u16x4*)(ABC + r * 768 + d0);
  f32x4 bias = *(const f32x4*)&b1[d0];

  const int* jr = ji + r * 4;
  const int* kr = ki + r * 4;
  int j0 = __builtin_amdgcn_readfirstlane(jr[0]);
  int j1 = __builtin_amdgcn_readfirstlane(jr[1]);
  int j2 = __builtin_amdgcn_readfirstlane(jr[2]);
  int j3 = __builtin_amdgcn_readfirstlane(jr[3]);
  int k0 = __builtin_amdgcn_readfirstlane(kr[0]);
  int k1 = __builtin_amdgcn_readfirstlane(kr[1]);
  int k2 = __builtin_amdgcn_readfirstlane(kr[2]);
  int k3 = __builtin_amdgcn_readfirstlane(kr[3]);

  u16x4 bv0 = *(const u16x4*)(ABC + (size_t)(base + j0) * 768 + 256 + d0);
  u16x4 bv1 = *(const u16x4*)(ABC + (size_t)(base + j1) * 768 + 256 + d0);
  u16x4 bv2 = *(const u16x4*)(ABC + (size_t)(base + j2) * 768 + 256 + d0);
  u16x4 bv3 = *(const u16x4*)(ABC + (size_t)(base + j3) * 768 + 256 + d0);
  u16x4 cv0 = *(const u16x4*)(ABC + (size_t)(base + k0) * 768 + 512 + d0);
  u16x4 cv1 = *(const u16x4*)(ABC + (size_t)(base + k1) * 768 + 512 + d0);
  u16x4 cv2 = *(const u16x4*)(ABC + (size_t)(base + k2) * 768 + 512 + d0);
  u16x4 cv3 = *(const u16x4*)(ABC + (size_t)(base + k3) * 768 + 512 + d0);

  float a0 = bf2f(av[0]) + bias[0];
  float a1 = bf2f(av[1]) + bias[1];
  float a2 = bf2f(av[2]) + bias[2];
  float a3 = bf2f(av[3]) + bias[3];

  float acc0, acc1, acc2, acc3;
  {
    float x0 = a0 + bf2f(bv0[0]) + bf2f(cv0[0]);
    float x1 = a1 + bf2f(bv0[1]) + bf2f(cv0[1]);
    float x2 = a2 + bf2f(bv0[2]) + bf2f(cv0[2]);
    float x3 = a3 + bf2f(bv0[3]) + bf2f(cv0[3]);
    acc0 = gelu_fast(x0); acc1 = gelu_fast(x1);
    acc2 = gelu_fast(x2); acc3 = gelu_fast(x3);
  }
  {
    float x0 = a0 + bf2f(bv1[0]) + bf2f(cv1[0]);
    float x1 = a1 + bf2f(bv1[1]) + bf2f(cv1[1]);
    float x2 = a2 + bf2f(bv1[2]) + bf2f(cv1[2]);
    float x3 = a3 + bf2f(bv1[3]) + bf2f(cv1[3]);
    acc0 += gelu_fast(x0); acc1 += gelu_fast(x1);
    acc2 += gelu_fast(x2); acc3 += gelu_fast(x3);
  }
  {
    float x0 = a0 + bf2f(bv2[0]) + bf2f(cv2[0]);
    float x1 = a1 + bf2f(bv2[1]) + bf2f(cv2[1]);
    float x2 = a2 + bf2f(bv2[2]) + bf2f(cv2[2]);
    float x3 = a3 + bf2f(bv2[3]) + bf2f(cv2[3]);
    acc0 += gelu_fast(x0); acc1 += gelu_fast(x1);
    acc2 += gelu_fast(x2); acc3 += gelu_fast(x3);
  }
  {
    float x0 = a0 + bf2f(bv3[0]) + bf2f(cv3[0]);
    float x1 = a1 + bf2f(bv3[1]) + bf2f(cv3[1]);
    float x2 = a2 + bf2f(bv3[2]) + bf2f(cv3[2]);
    float x3 = a3 + bf2f(bv3[3]) + bf2f(cv3[3]);
    acc0 += gelu_fast(x0); acc1 += gelu_fast(x1);
    acc2 += gelu_fast(x2); acc3 += gelu_fast(x3);
  }

  u16x4 hv;
  hv[0] = f2bf(acc0 * 0.25f);
  hv[1] = f2bf(acc1 * 0.25f);
  hv[2] = f2bf(acc2 * 0.25f);
  hv[3] = f2bf(acc3 * 0.25f);
  *(u16x4*)(Hm + r * 256 + d0) = hv;
}

// ---------------------------------------------------------------------------
extern "C" void kernel_launch(void* const* d_in, const int* in_sizes, int n_in,
                              void* d_out, int out_size, void* d_ws, size_t ws_size,
                              hipStream_t stream) {
  (void)in_sizes; (void)n_in; (void)out_size; (void)ws_size;
  const float* x  = (const float*)d_in[0];
  const int*   ji = (const int*)d_in[1];
  const int*   ki = (const int*)d_in[2];
  const float* W1 = (const float*)d_in[3];
  const float* b1 = (const float*)d_in[4];
  const float* W2 = (const float*)d_in[5];
  const float* b2 = (const float*)d_in[6];
  float* out = (float*)d_out;

  char* ws = (char*)d_ws;
  u16* ABC = (u16*)ws;  ws += (size_t)MTOT * 768 * 2;   // 100.7 MB
  u16* Hm  = (u16*)ws;  ws += (size_t)MTOT * 256 * 2;   // 33.5 MB
  u16* W1t = (u16*)ws;  ws += 768 * 256 * 2;
  u16* W2t = (u16*)ws;  ws += 256 * 256 * 2;

  prep_w<<<1024, 256, 0, stream>>>(W1, W2, W1t, W2t);

  gemm1f<<<(MTOT / 128) * 6, 256, 0, stream>>>(x, W1t, ABC);

  gather_gelu_mean<<<MTOT / 4, 256, 0, stream>>>(ABC, ji, ki, b1, Hm);

  gemm2k<<<(MTOT / 128) * 2, 256, 0, stream>>>(Hm, W2t, out, b2);
}

// Round 12
// 124.953 us; speedup vs baseline: 1.0388x; 1.0204x over previous
//
#include <hip/hip_runtime.h>
#include <hip/hip_bf16.h>

#define Bb 8
#define Nn 8192
#define Ss 4
#define Dd 256
#define MTOT (Bb*Nn)   // 65536

typedef unsigned short u16;
typedef short short8 __attribute__((ext_vector_type(8)));
typedef unsigned short u16x4 __attribute__((ext_vector_type(4)));
typedef float f32x4 __attribute__((ext_vector_type(4)));

static __device__ __forceinline__ float bf2f(u16 v) {
  union { unsigned int u; float f; } x; x.u = ((unsigned int)v) << 16; return x.f;
}
static __device__ __forceinline__ u16 f2bf(float f) {
  union { float f; unsigned int u; } x; x.f = f;
  unsigned int u = x.u;
  return (u16)((u + 0x7fffu + ((u >> 16) & 1u)) >> 16);  // RNE
}
static __device__ __forceinline__ void glds16(const u16* g, u16* l) {
  __builtin_amdgcn_global_load_lds(
      (const __attribute__((address_space(1))) void*)g,
      (__attribute__((address_space(3))) void*)l, 16, 0, 0);
}

// tanh-form GELU as a sigmoid
static __device__ __forceinline__ float gelu_fast(float x) {
  float x2 = x * x;
  float z = x * (-2.3021277f - 0.10294456f * x2);
  float e = __builtin_amdgcn_exp2f(z);
  return x * __builtin_amdgcn_rcpf(1.0f + e);
}

// ---------------------------------------------------------------------------
// prep: x (f32) -> xb (bf16); W1 -> W1t bf16 (transposed); W2 -> W2t bf16.
// (measured at HBM roofline — 100 MB at ~6.25 TB/s)
// ---------------------------------------------------------------------------
__global__ __launch_bounds__(256) void prep_kernel(
    const float* __restrict__ x, const float* __restrict__ W1,
    const float* __restrict__ W2,
    u16* __restrict__ xb, u16* __restrict__ W1t, u16* __restrict__ W2t)
{
  int bid = blockIdx.x, t = threadIdx.x;
  if (bid < 16384) {
    size_t i = ((size_t)bid * 256 + t) * 4;
    f32x4 v = *(const f32x4*)&x[i];
    u16x4 o;
    o[0] = f2bf(v[0]); o[1] = f2bf(v[1]); o[2] = f2bf(v[2]); o[3] = f2bf(v[3]);
    *(u16x4*)&xb[i] = o;
  } else if (bid < 16384 + 768) {
    int j = (bid - 16384) * 256 + t;   // j = n*256 + k
    int n = j >> 8, k = j & 255;
    int tb = n >> 8, d = n & 255;
    W1t[j] = f2bf(W1[(size_t)(tb * 256 + k) * 256 + d]);
  } else {
    int j = (bid - 17152) * 256 + t;
    int n = j >> 8, k = j & 255;
    W2t[j] = f2bf(W2[(size_t)k * 256 + n]);
  }
}

// ---------------------------------------------------------------------------
// 128x128-tile bf16 MFMA GEMM, K=256, BK=64, 4 waves (2x2).
// T3-minimum 2-phase pipeline: double-buffered LDS; stage kt+1 BEFORE
// computing kt; ONE __syncthreads per kt (its implicit vmcnt(0) drains the
// just-issued next-tile glds while this tile's ds_read+MFMA overlapped the
// flight).  1D grid, n-inner, XCD-chunk swizzle; T2 LDS swizzle via
// pre-swizzled global source + XOR'd ds_read address.
// MODE 0: out bf16. MODE 1: out f32 + bias.
// ---------------------------------------------------------------------------
template<int MODE, int NBLK>
__global__ __launch_bounds__(256) void gemm128(
    const u16* __restrict__ Ag, const u16* __restrict__ Btg,
    void* __restrict__ Outv, const float* __restrict__ bias, int ldOut)
{
  __shared__ u16 As[2][128 * 64];
  __shared__ u16 Bs[2][128 * 64];
  const int t = threadIdx.x;
  const int w = t >> 6, lane = t & 63;
  const int wm = (w >> 1) * 64, wn = (w & 1) * 64;
  const int lr = lane & 15;
  const int lk = (lane >> 4) * 8;

  const int cpx = gridDim.x >> 3;
  const int bid = blockIdx.x;
  const int swz = (bid & 7) * cpx + (bid >> 3);
  const int n0 = (swz % NBLK) * 128;
  const size_t m0 = (size_t)(swz / NBLK) * 128;

  auto stage = [&](int buf, int kt) {
#pragma unroll
    for (int pass = 0; pass < 4; ++pass) {
      int c = pass * 256 + t;
      int row = c >> 3, cc = c & 7;
      int scc = cc ^ (row & 7);
      glds16(Ag + (m0 + row) * 256 + kt * 64 + scc * 8,
             &As[buf][pass * 2048 + (t & 192) * 8]);
      glds16(Btg + (size_t)(n0 + row) * 256 + kt * 64 + scc * 8,
             &Bs[buf][pass * 2048 + (t & 192) * 8]);
    }
  };

  f32x4 acc[4][4];
#pragma unroll
  for (int m = 0; m < 4; ++m)
#pragma unroll
    for (int n = 0; n < 4; ++n)
      acc[m][n] = (f32x4){0.f, 0.f, 0.f, 0.f};

  stage(0, 0);
  __syncthreads();

  for (int kt = 0; kt < 4; ++kt) {
    int cur = kt & 1;
    if (kt < 3) stage(cur ^ 1, kt + 1);   // next tile in flight over compute
#pragma unroll
    for (int kk = 0; kk < 2; ++kk) {
      short8 af[4], bfr[4];
#pragma unroll
      for (int m = 0; m < 4; ++m) {
        int rA = wm + m * 16 + lr;
        af[m] = *(const short8*)&As[cur][(rA * 64 + kk * 32 + lk) ^ ((rA & 7) << 3)];
      }
#pragma unroll
      for (int n = 0; n < 4; ++n) {
        int rB = wn + n * 16 + lr;
        bfr[n] = *(const short8*)&Bs[cur][(rB * 64 + kk * 32 + lk) ^ ((rB & 7) << 3)];
      }
#pragma unroll
      for (int m = 0; m < 4; ++m)
#pragma unroll
        for (int n = 0; n < 4; ++n)
          acc[m][n] = __builtin_amdgcn_mfma_f32_16x16x32_bf16(
              af[m], bfr[n], acc[m][n], 0, 0, 0);
    }
    __syncthreads();   // implicit vmcnt(0)+lgkmcnt(0): next tile ready
  }

  // epilogue: C/D layout col = lane&15, row = (lane>>4)*4 + reg
#pragma unroll
  for (int m = 0; m < 4; ++m) {
    int rbase = wm + m * 16 + ((lane >> 4) << 2);
#pragma unroll
    for (int n = 0; n < 4; ++n) {
      int col = n0 + wn + n * 16 + (lane & 15);
#pragma unroll
      for (int rr = 0; rr < 4; ++rr) {
        size_t row = m0 + rbase + rr;
        if (MODE == 0) {
          ((u16*)Outv)[row * (size_t)ldOut + col] = f2bf(acc[m][n][rr]);
        } else {
          ((float*)Outv)[row * (size_t)ldOut + col] = acc[m][n][rr] + bias[col];
        }
      }
    }
  }
}

// ---------------------------------------------------------------------------
// gather + fast GELU + mean over S (R9 form: SGPR indices, 8 gathers in
// flight, chunked XCD swizzle — measured at its mixed VALU/memory point).
// ---------------------------------------------------------------------------
__global__ __launch_bounds__(256) void gather_gelu_mean(
    const u16* __restrict__ ABC, const int* __restrict__ ji,
    const int* __restrict__ ki, const float* __restrict__ b1,
    u16* __restrict__ Hm)
{
  int t = threadIdx.x, w = t >> 6, lane = t & 63;
  const int cpx = gridDim.x >> 3;
  const int bid = blockIdx.x;
  const int swz = (bid & 7) * cpx + (bid >> 3);
  size_t r = (size_t)swz * 4 + w;
  int base = ((int)(r >> 13)) << 13;   // batch row offset
  int d0 = lane * 4;

  u16x4 av = *(const u16x4*)(ABC + r * 768 + d0);
  f32x4 bias = *(const f32x4*)&b1[d0];

  const int* jr = ji + r * 4;
  const int* kr = ki + r * 4;
  int j0 = __builtin_amdgcn_readfirstlane(jr[0]);
  int j1 = __builtin_amdgcn_readfirstlane(jr[1]);
  int j2 = __builtin_amdgcn_readfirstlane(jr[2]);
  int j3 = __builtin_amdgcn_readfirstlane(jr[3]);
  int k0 = __builtin_amdgcn_readfirstlane(kr[0]);
  int k1 = __builtin_amdgcn_readfirstlane(kr[1]);
  int k2 = __builtin_amdgcn_readfirstlane(kr[2]);
  int k3 = __builtin_amdgcn_readfirstlane(kr[3]);

  u16x4 bv0 = *(const u16x4*)(ABC + (size_t)(base + j0) * 768 + 256 + d0);
  u16x4 bv1 = *(const u16x4*)(ABC + (size_t)(base + j1) * 768 + 256 + d0);
  u16x4 bv2 = *(const u16x4*)(ABC + (size_t)(base + j2) * 768 + 256 + d0);
  u16x4 bv3 = *(const u16x4*)(ABC + (size_t)(base + j3) * 768 + 256 + d0);
  u16x4 cv0 = *(const u16x4*)(ABC + (size_t)(base + k0) * 768 + 512 + d0);
  u16x4 cv1 = *(const u16x4*)(ABC + (size_t)(base + k1) * 768 + 512 + d0);
  u16x4 cv2 = *(const u16x4*)(ABC + (size_t)(base + k2) * 768 + 512 + d0);
  u16x4 cv3 = *(const u16x4*)(ABC + (size_t)(base + k3) * 768 + 512 + d0);

  float a0 = bf2f(av[0]) + bias[0];
  float a1 = bf2f(av[1]) + bias[1];
  float a2 = bf2f(av[2]) + bias[2];
  float a3 = bf2f(av[3]) + bias[3];

  float acc0, acc1, acc2, acc3;
  {
    float x0 = a0 + bf2f(bv0[0]) + bf2f(cv0[0]);
    float x1 = a1 + bf2f(bv0[1]) + bf2f(cv0[1]);
    float x2 = a2 + bf2f(bv0[2]) + bf2f(cv0[2]);
    float x3 = a3 + bf2f(bv0[3]) + bf2f(cv0[3]);
    acc0 = gelu_fast(x0); acc1 = gelu_fast(x1);
    acc2 = gelu_fast(x2); acc3 = gelu_fast(x3);
  }
  {
    float x0 = a0 + bf2f(bv1[0]) + bf2f(cv1[0]);
    float x1 = a1 + bf2f(bv1[1]) + bf2f(cv1[1]);
    float x2 = a2 + bf2f(bv1[2]) + bf2f(cv1[2]);
    float x3 = a3 + bf2f(bv1[3]) + bf2f(cv1[3]);
    acc0 += gelu_fast(x0); acc1 += gelu_fast(x1);
    acc2 += gelu_fast(x2); acc3 += gelu_fast(x3);
  }
  {
    float x0 = a0 + bf2f(bv2[0]) + bf2f(cv2[0]);
    float x1 = a1 + bf2f(bv2[1]) + bf2f(cv2[1]);
    float x2 = a2 + bf2f(bv2[2]) + bf2f(cv2[2]);
    float x3 = a3 + bf2f(bv2[3]) + bf2f(cv2[3]);
    acc0 += gelu_fast(x0); acc1 += gelu_fast(x1);
    acc2 += gelu_fast(x2); acc3 += gelu_fast(x3);
  }
  {
    float x0 = a0 + bf2f(bv3[0]) + bf2f(cv3[0]);
    float x1 = a1 + bf2f(bv3[1]) + bf2f(cv3[1]);
    float x2 = a2 + bf2f(bv3[2]) + bf2f(cv3[2]);
    float x3 = a3 + bf2f(bv3[3]) + bf2f(cv3[3]);
    acc0 += gelu_fast(x0); acc1 += gelu_fast(x1);
    acc2 += gelu_fast(x2); acc3 += gelu_fast(x3);
  }

  u16x4 hv;
  hv[0] = f2bf(acc0 * 0.25f);
  hv[1] = f2bf(acc1 * 0.25f);
  hv[2] = f2bf(acc2 * 0.25f);
  hv[3] = f2bf(acc3 * 0.25f);
  *(u16x4*)(Hm + r * 256 + d0) = hv;
}

// ---------------------------------------------------------------------------
extern "C" void kernel_launch(void* const* d_in, const int* in_sizes, int n_in,
                              void* d_out, int out_size, void* d_ws, size_t ws_size,
                              hipStream_t stream) {
  (void)in_sizes; (void)n_in; (void)out_size; (void)ws_size;
  const float* x  = (const float*)d_in[0];
  const int*   ji = (const int*)d_in[1];
  const int*   ki = (const int*)d_in[2];
  const float* W1 = (const float*)d_in[3];
  const float* b1 = (const float*)d_in[4];
  const float* W2 = (const float*)d_in[5];
  const float* b2 = (const float*)d_in[6];
  float* out = (float*)d_out;

  char* ws = (char*)d_ws;
  u16* xb  = (u16*)ws;  ws += (size_t)MTOT * 256 * 2;   // 33.5 MB
  u16* ABC = (u16*)ws;  ws += (size_t)MTOT * 768 * 2;   // 100.7 MB
  u16* Hm  = (u16*)ws;  ws += (size_t)MTOT * 256 * 2;   // 33.5 MB
  u16* W1t = (u16*)ws;  ws += 768 * 256 * 2;
  u16* W2t = (u16*)ws;  ws += 256 * 256 * 2;

  prep_kernel<<<17408, 256, 0, stream>>>(x, W1, W2, xb, W1t, W2t);

  gemm128<0, 6><<<(MTOT / 128) * 6, 256, 0, stream>>>(
      xb, W1t, (void*)ABC, nullptr, 768);

  gather_gelu_mean<<<MTOT / 4, 256, 0, stream>>>(ABC, ji, ki, b1, Hm);

  gemm128<1, 2><<<(MTOT / 128) * 2, 256, 0, stream>>>(
      Hm, W2t, (void*)out, b2, 256);
}

// Round 13
// 119.903 us; speedup vs baseline: 1.0825x; 1.0421x over previous
//
#include <hip/hip_runtime.h>
#include <hip/hip_bf16.h>

#define Bb 8
#define Nn 8192
#define Ss 4
#define Dd 256
#define MTOT (Bb*Nn)   // 65536

typedef unsigned short u16;
typedef short short8 __attribute__((ext_vector_type(8)));
typedef unsigned short u16x4 __attribute__((ext_vector_type(4)));
typedef float f32x4 __attribute__((ext_vector_type(4)));

static __device__ __forceinline__ float bf2f(u16 v) {
  union { unsigned int u; float f; } x; x.u = ((unsigned int)v) << 16; return x.f;
}
static __device__ __forceinline__ u16 f2bf(float f) {
  union { float f; unsigned int u; } x; x.f = f;
  unsigned int u = x.u;
  return (u16)((u + 0x7fffu + ((u >> 16) & 1u)) >> 16);  // RNE
}

// tanh-form GELU as a sigmoid: gelu(x) = x * sigmoid(1.5957691*(x + 0.044715 x^3))
static __device__ __forceinline__ float gelu_fast(float x) {
  float x2 = x * x;
  float z = x * (-2.3021277f - 0.10294456f * x2);
  float e = __builtin_amdgcn_exp2f(z);
  return x * __builtin_amdgcn_rcpf(1.0f + e);
}

// ---------------------------------------------------------------------------
// prep: x (f32) -> xb (bf16); W1 -> W1t bf16 (transposed); W2 -> W2t bf16.
// Measured at HBM roofline (~100 MB streamed).
// ---------------------------------------------------------------------------
__global__ __launch_bounds__(256) void prep_kernel(
    const float* __restrict__ x, const float* __restrict__ W1,
    const float* __restrict__ W2,
    u16* __restrict__ xb, u16* __restrict__ W1t, u16* __restrict__ W2t)
{
  int bid = blockIdx.x, t = threadIdx.x;
  if (bid < 16384) {
    size_t i = ((size_t)bid * 256 + t) * 4;
    f32x4 v = *(const f32x4*)&x[i];
    u16x4 o;
    o[0] = f2bf(v[0]); o[1] = f2bf(v[1]); o[2] = f2bf(v[2]); o[3] = f2bf(v[3]);
    *(u16x4*)&xb[i] = o;
  } else if (bid < 16384 + 768) {
    int j = (bid - 16384) * 256 + t;   // j = n*256 + k
    int n = j >> 8, k = j & 255;
    int tb = n >> 8, d = n & 255;
    W1t[j] = f2bf(W1[(size_t)(tb * 256 + k) * 256 + d]);
  } else {
    int j = (bid - 17152) * 256 + t;
    int n = j >> 8, k = j & 255;
    W2t[j] = f2bf(W2[(size_t)k * 256 + n]);
  }
}

// ---------------------------------------------------------------------------
// 128x128-tile bf16 MFMA GEMM, K=256, BK=64, 4 waves (2x2), single-buffer
// (dbuf measured NEGATIVE here: occupancy trade, R12).
// 1D grid, n-inner, XCD-chunk swizzle; T2 LDS swizzle via pre-swizzled
// global source + XOR'd ds_read address (bank conflicts 9.4M -> 0, R4).
// MODE 0: out bf16. MODE 1: out f32 + bias.
// ---------------------------------------------------------------------------
template<int MODE, int NBLK>
__global__ __launch_bounds__(256) void gemm128(
    const u16* __restrict__ Ag, const u16* __restrict__ Btg,
    void* __restrict__ Outv, const float* __restrict__ bias, int ldOut)
{
  __shared__ u16 As[128 * 64];
  __shared__ u16 Bs[128 * 64];
  const int t = threadIdx.x;
  const int w = t >> 6, lane = t & 63;
  const int wm = (w >> 1) * 64, wn = (w & 1) * 64;
  const int lr = lane & 15;
  const int lk = (lane >> 4) * 8;

  const int cpx = gridDim.x >> 3;
  const int bid = blockIdx.x;
  const int swz = (bid & 7) * cpx + (bid >> 3);
  const int n0 = (swz % NBLK) * 128;
  const size_t m0 = (size_t)(swz / NBLK) * 128;

  f32x4 acc[4][4];
#pragma unroll
  for (int m = 0; m < 4; ++m)
#pragma unroll
    for (int n = 0; n < 4; ++n)
      acc[m][n] = (f32x4){0.f, 0.f, 0.f, 0.f};

  for (int kt = 0; kt < 4; ++kt) {
#pragma unroll
    for (int pass = 0; pass < 4; ++pass) {
      int c = pass * 256 + t;
      int row = c >> 3, cc = c & 7;
      int scc = cc ^ (row & 7);
      const u16* ga = Ag + (m0 + row) * 256 + kt * 64 + scc * 8;
      u16* la = As + pass * 2048 + (t & 192) * 8;
      __builtin_amdgcn_global_load_lds(
          (const __attribute__((address_space(1))) void*)ga,
          (__attribute__((address_space(3))) void*)la, 16, 0, 0);
      const u16* gb = Btg + (size_t)(n0 + row) * 256 + kt * 64 + scc * 8;
      u16* lb = Bs + pass * 2048 + (t & 192) * 8;
      __builtin_amdgcn_global_load_lds(
          (const __attribute__((address_space(1))) void*)gb,
          (__attribute__((address_space(3))) void*)lb, 16, 0, 0);
    }
    __syncthreads();
#pragma unroll
    for (int kk = 0; kk < 2; ++kk) {
      short8 af[4], bfr[4];
#pragma unroll
      for (int m = 0; m < 4; ++m) {
        int rA = wm + m * 16 + lr;
        af[m] = *(const short8*)&As[(rA * 64 + kk * 32 + lk) ^ ((rA & 7) << 3)];
      }
#pragma unroll
      for (int n = 0; n < 4; ++n) {
        int rB = wn + n * 16 + lr;
        bfr[n] = *(const short8*)&Bs[(rB * 64 + kk * 32 + lk) ^ ((rB & 7) << 3)];
      }
#pragma unroll
      for (int m = 0; m < 4; ++m)
#pragma unroll
        for (int n = 0; n < 4; ++n)
          acc[m][n] = __builtin_amdgcn_mfma_f32_16x16x32_bf16(
              af[m], bfr[n], acc[m][n], 0, 0, 0);
    }
    __syncthreads();
  }

#pragma unroll
  for (int m = 0; m < 4; ++m) {
    int rbase = wm + m * 16 + ((lane >> 4) << 2);
#pragma unroll
    for (int n = 0; n < 4; ++n) {
      int col = n0 + wn + n * 16 + (lane & 15);
#pragma unroll
      for (int rr = 0; rr < 4; ++rr) {
        size_t row = m0 + rbase + rr;
        if (MODE == 0) {
          ((u16*)Outv)[row * (size_t)ldOut + col] = f2bf(acc[m][n][rr]);
        } else {
          ((float*)Outv)[row * (size_t)ldOut + col] = acc[m][n][rr] + bias[col];
        }
      }
    }
  }
}

// ---------------------------------------------------------------------------
// gather + fast GELU + mean over S (one wave per output row, max TLP).
// Chunked XCD swizzle: 2048 consecutive logical blocks = one batch.
// Measured at its mixed VALU/memory operating point (R7/R9 nulls).
// ---------------------------------------------------------------------------
__global__ __launch_bounds__(256) void gather_gelu_mean(
    const u16* __restrict__ ABC, const int* __restrict__ ji,
    const int* __restrict__ ki, const float* __restrict__ b1,
    u16* __restrict__ Hm)
{
  int t = threadIdx.x, w = t >> 6, lane = t & 63;
  const int cpx = gridDim.x >> 3;   // 2048 = one batch per XCD chunk
  const int bid = blockIdx.x;
  const int swz = (bid & 7) * cpx + (bid >> 3);
  size_t r = (size_t)swz * 4 + w;
  int base = ((int)(r >> 13)) << 13;   // batch row offset
  int d0 = lane * 4;

  f32x4 bias = *(const f32x4*)&b1[d0];
  u16x4 av = *(const u16x4*)(ABC + r * 768 + d0);
  float a0 = bf2f(av[0]) + bias[0];
  float a1 = bf2f(av[1]) + bias[1];
  float a2 = bf2f(av[2]) + bias[2];
  float a3 = bf2f(av[3]) + bias[3];

  const int* jr = ji + r * 4;
  const int* kr = ki + r * 4;
  float acc0 = 0.f, acc1 = 0.f, acc2 = 0.f, acc3 = 0.f;
#pragma unroll
  for (int s = 0; s < 4; ++s) {
    size_t gj = (size_t)(base + jr[s]);
    size_t gk = (size_t)(base + kr[s]);
    u16x4 bv = *(const u16x4*)(ABC + gj * 768 + 256 + d0);
    u16x4 cv = *(const u16x4*)(ABC + gk * 768 + 512 + d0);
    float x0 = a0 + bf2f(bv[0]) + bf2f(cv[0]);
    float x1 = a1 + bf2f(bv[1]) + bf2f(cv[1]);
    float x2 = a2 + bf2f(bv[2]) + bf2f(cv[2]);
    float x3 = a3 + bf2f(bv[3]) + bf2f(cv[3]);
    acc0 += gelu_fast(x0);
    acc1 += gelu_fast(x1);
    acc2 += gelu_fast(x2);
    acc3 += gelu_fast(x3);
  }
  u16x4 hv;
  hv[0] = f2bf(acc0 * 0.25f);
  hv[1] = f2bf(acc1 * 0.25f);
  hv[2] = f2bf(acc2 * 0.25f);
  hv[3] = f2bf(acc3 * 0.25f);
  *(u16x4*)(Hm + r * 256 + d0) = hv;
}

// ---------------------------------------------------------------------------
extern "C" void kernel_launch(void* const* d_in, const int* in_sizes, int n_in,
                              void* d_out, int out_size, void* d_ws, size_t ws_size,
                              hipStream_t stream) {
  (void)in_sizes; (void)n_in; (void)out_size; (void)ws_size;
  const float* x  = (const float*)d_in[0];
  const int*   ji = (const int*)d_in[1];
  const int*   ki = (const int*)d_in[2];
  const float* W1 = (const float*)d_in[3];
  const float* b1 = (const float*)d_in[4];
  const float* W2 = (const float*)d_in[5];
  const float* b2 = (const float*)d_in[6];
  float* out = (float*)d_out;

  char* ws = (char*)d_ws;
  u16* xb  = (u16*)ws;  ws += (size_t)MTOT * 256 * 2;   // 33.5 MB
  u16* ABC = (u16*)ws;  ws += (size_t)MTOT * 768 * 2;   // 100.7 MB
  u16* Hm  = (u16*)ws;  ws += (size_t)MTOT * 256 * 2;   // 33.5 MB
  u16* W1t = (u16*)ws;  ws += 768 * 256 * 2;
  u16* W2t = (u16*)ws;  ws += 256 * 256 * 2;

  prep_kernel<<<17408, 256, 0, stream>>>(x, W1, W2, xb, W1t, W2t);

  gemm128<0, 6><<<(MTOT / 128) * 6, 256, 0, stream>>>(
      xb, W1t, (void*)ABC, nullptr, 768);

  gather_gelu_mean<<<MTOT / 4, 256, 0, stream>>>(ABC, ji, ki, b1, Hm);

  gemm128<1, 2><<<(MTOT / 128) * 2, 256, 0, stream>>>(
      Hm, W2t, (void*)out, b2, 256);
}